// Round 4
// baseline (1170.339 us; speedup 1.0000x reference)
//
#include <hip/hip_runtime.h>

#define Hh 64
#define INPUT 3
#define OUTD 2
#define BATCH 1024
#define NB 4                 // batches per block
#define TENC 512
#define PLEN 300

#define LOG2E 1.44269504088896340736f

__device__ __forceinline__ float tanh_(float x) {
    float t = __builtin_amdgcn_exp2f(x * (2.0f * LOG2E));
    return fmaf(-2.0f, __builtin_amdgcn_rcpf(1.0f + t), 1.0f);
}

// quad-broadcast via DPP: every lane of a quad gets quad-lane Q's value
#define QUADB(dst, src, pat)                                                   \
    dst = __int_as_float(__builtin_amdgcn_update_dpp(                          \
        0, __float_as_int(src), (pat), 0xF, 0xF, true))

// 4 k-MACs for all 4 batches; hb points at h_s[rp] ([batch][unit] layout)
#define MACK(W, K)                                                             \
    {                                                                          \
        const float4 hv0 = *reinterpret_cast<const float4*>(hb + 0 * Hh + (K));\
        const float4 hv1 = *reinterpret_cast<const float4*>(hb + 1 * Hh + (K));\
        const float4 hv2 = *reinterpret_cast<const float4*>(hb + 2 * Hh + (K));\
        const float4 hv3 = *reinterpret_cast<const float4*>(hb + 3 * Hh + (K));\
        aa0 = fmaf((W).x, hv0.x, aa0); ab0 = fmaf((W).y, hv0.y, ab0);          \
        aa0 = fmaf((W).z, hv0.z, aa0); ab0 = fmaf((W).w, hv0.w, ab0);          \
        aa1 = fmaf((W).x, hv1.x, aa1); ab1 = fmaf((W).y, hv1.y, ab1);          \
        aa1 = fmaf((W).z, hv1.z, aa1); ab1 = fmaf((W).w, hv1.w, ab1);          \
        aa2 = fmaf((W).x, hv2.x, aa2); ab2 = fmaf((W).y, hv2.y, ab2);          \
        aa2 = fmaf((W).z, hv2.z, aa2); ab2 = fmaf((W).w, hv2.w, ab2);          \
        aa3 = fmaf((W).x, hv3.x, aa3); ab3 = fmaf((W).y, hv3.y, ab3);          \
        aa3 = fmaf((W).z, hv3.z, aa3); ab3 = fmaf((W).w, hv3.w, ab3);          \
    }

__global__ __launch_bounds__(256, 1)
void lstm_forecast_kernel(const float* __restrict__ x,
                          const float* __restrict__ force,
                          const float* __restrict__ W_ih,
                          const float* __restrict__ W_hh,
                          const float* __restrict__ b_ih,
                          const float* __restrict__ b_hh,
                          const float* __restrict__ W_out,
                          const float* __restrict__ b_out,
                          float* __restrict__ out)
{
    const int tid  = threadIdx.x;
    const int g    = tid & 3;           // gate 0=i 1=f 2=g 3=o (quad-local)
    const int lane = tid & 63;
    const int ul   = lane >> 2;         // unit-local 0..15
    const int wv   = tid >> 6;          // wave 0..3
    const int u    = wv * 16 + ul;      // hidden unit 0..63
    const int r    = (g << 6) + u;      // weight row
    const int b0   = blockIdx.x * NB;   // first batch of this block

    __shared__ __align__(16) float xc_s[TENC * INPUT * NB];    // 24 KB [t][c][b]
    __shared__ __align__(16) float fc_s[(PLEN - 1) * NB];      // ~4.7 KB [d][b]
    __shared__ __align__(16) float h_s[2][NB * Hh];            // 2 KB  [ph][b][u]
    __shared__ __align__(16) float y_s[2][NB][4][2];           // 256 B [ph][b][wv][g]

    // ---- stage x: x[b][t][c] -> xc_s[t][c][b] (coalesced reads) ----
    for (int i = tid; i < TENC * INPUT * NB; i += 256) {
        const int bb  = i / (TENC * INPUT);
        const int rem = i - bb * (TENC * INPUT);
        const int t   = rem / INPUT;
        const int c_  = rem - t * INPUT;
        xc_s[t * (INPUT * NB) + c_ * NB + bb] =
            x[(size_t)(b0 + bb) * (TENC * INPUT) + rem];
    }
    // ---- stage force: force[b][d] -> fc_s[d][b] ----
    for (int i = tid; i < (PLEN - 1) * NB; i += 256) {
        const int bb = i / (PLEN - 1);
        const int d  = i - bb * (PLEN - 1);
        fc_s[d * NB + bb] = force[(size_t)(b0 + bb) * (PLEN - 1) + d];
    }
    h_s[0][tid] = 0.0f;   // 256 = NB*Hh

    // ---- per-thread weights: 16 named float4 (row r of W_hh) ----
    const float4* wrow = reinterpret_cast<const float4*>(W_hh + (size_t)r * Hh);
    const float4 w0 = wrow[0],  w1 = wrow[1],  w2 = wrow[2],  w3 = wrow[3];
    const float4 w4 = wrow[4],  w5 = wrow[5],  w6 = wrow[6],  w7 = wrow[7];
    const float4 w8 = wrow[8],  w9 = wrow[9],  wA = wrow[10], wB = wrow[11];
    const float4 wC = wrow[12], wD = wrow[13], wE = wrow[14], wF = wrow[15];

    const float wi0  = W_ih[r * INPUT + 0];
    const float wi1  = W_ih[r * INPUT + 1];
    const float wi2  = W_ih[r * INPUT + 2];
    const float bias = b_ih[r] + b_hh[r];

    // branch-free activation constants: a = am * rcp(1 + 2^(acc*kmul)) + acK
    const float kmul = (g == 2) ? (-2.0f * LOG2E) : (-LOG2E);
    const float am   = (g == 2) ? 2.0f : 1.0f;
    const float acK  = (g == 2) ? -1.0f : 0.0f;

    const float wog = (g == 1) ? W_out[Hh + u] : W_out[u];  // valid for g<2
    const float bo0 = b_out[0], bo1 = b_out[1];

    float c0 = 0.0f, c1 = 0.0f, c2 = 0.0f, c3 = 0.0f;
    int   rp = 0;

    __syncthreads();

    // one step for all 4 batches; inputs per batch in float4 components
    auto lstm_step = [&](float4 xc0, float4 xc1, float4 xc2, bool do_y) {
        const float* hb = h_s[rp];
        float aa0 = fmaf(wi0, xc0.x, bias);
        float aa1 = fmaf(wi0, xc0.y, bias);
        float aa2 = fmaf(wi0, xc0.z, bias);
        float aa3 = fmaf(wi0, xc0.w, bias);
        float ab0 = wi1 * xc1.x, ab1 = wi1 * xc1.y;
        float ab2 = wi1 * xc1.z, ab3 = wi1 * xc1.w;
        aa0 = fmaf(wi2, xc2.x, aa0); aa1 = fmaf(wi2, xc2.y, aa1);
        aa2 = fmaf(wi2, xc2.z, aa2); aa3 = fmaf(wi2, xc2.w, aa3);

        MACK(w0, 0)  MACK(w1, 4)  MACK(w2, 8)  MACK(w3, 12)
        MACK(w4, 16) MACK(w5, 20) MACK(w6, 24) MACK(w7, 28)
        MACK(w8, 32) MACK(w9, 36) MACK(wA, 40) MACK(wB, 44)
        MACK(wC, 48) MACK(wD, 52) MACK(wE, 56) MACK(wF, 60)

        float h0, h1, h2, h3;
        #define GATEUPD(ACC0, ACC1, CC, HH)                                    \
        {                                                                      \
            const float acc = (ACC0) + (ACC1);                                 \
            const float e   = __builtin_amdgcn_exp2f(acc * kmul);              \
            const float rr  = __builtin_amdgcn_rcpf(1.0f + e);                 \
            const float a   = fmaf(am, rr, acK);                               \
            float gi, gf, gg, go;                                              \
            QUADB(gi, a, 0x00); QUADB(gf, a, 0x55);                            \
            QUADB(gg, a, 0xAA); QUADB(go, a, 0xFF);                            \
            CC = fmaf(gf, CC, gi * gg);                                        \
            HH = go * tanh_(CC);                                               \
        }
        GATEUPD(aa0, ab0, c0, h0)
        GATEUPD(aa1, ab1, c1, h1)
        GATEUPD(aa2, ab2, c2, h2)
        GATEUPD(aa3, ab3, c3, h3)
        #undef GATEUPD

        // every thread writes exactly one h: batch g, unit u
        const float hw = (g == 0) ? h0 : (g == 1) ? h1 : (g == 2) ? h2 : h3;
        h_s[rp ^ 1][(g << 6) + u] = hw;

        if (do_y) {
            // per-wave partials of y[g] (g<2), reduced over unit-local lanes
            float p0 = (g < 2) ? wog * h0 : 0.0f;
            float p1 = (g < 2) ? wog * h1 : 0.0f;
            float p2 = (g < 2) ? wog * h2 : 0.0f;
            float p3 = (g < 2) ? wog * h3 : 0.0f;
            #pragma unroll
            for (int m = 4; m <= 32; m <<= 1) {
                p0 += __shfl_xor(p0, m, 64);
                p1 += __shfl_xor(p1, m, 64);
                p2 += __shfl_xor(p2, m, 64);
                p3 += __shfl_xor(p3, m, 64);
            }
            if (g < 2 && ul < NB) {
                const float pw = (ul == 0) ? p0 : (ul == 1) ? p1
                               : (ul == 2) ? p2 : p3;
                y_s[rp ^ 1][ul][wv][g] = pw;
            }
        }
        rp ^= 1;
        __syncthreads();
    };

    // read y for all 4 batches from y_s[rp] (same-address broadcasts)
    float4 yv0, yv1;  // yv0 = y-out0 per batch, yv1 = y-out1 per batch
    auto read_y = [&]() {
        #define RDY(B, O0, O1)                                                 \
        {                                                                      \
            const float4 q0 = *reinterpret_cast<const float4*>(&y_s[rp][B][0][0]);\
            const float4 q1 = *reinterpret_cast<const float4*>(&y_s[rp][B][2][0]);\
            O0 = q0.x + q0.z + q1.x + q1.z + bo0;                              \
            O1 = q0.y + q0.w + q1.y + q1.w + bo1;                              \
        }
        RDY(0, yv0.x, yv1.x) RDY(1, yv0.y, yv1.y)
        RDY(2, yv0.z, yv1.z) RDY(3, yv0.w, yv1.w)
        #undef RDY
    };

    // ---- encoder ----
    for (int t = 0; t < TENC; ++t) {
        const float* xp = xc_s + t * (INPUT * NB);
        const float4 xc0 = *reinterpret_cast<const float4*>(xp + 0);
        const float4 xc1 = *reinterpret_cast<const float4*>(xp + NB);
        const float4 xc2 = *reinterpret_cast<const float4*>(xp + 2 * NB);
        lstm_step(xc0, xc1, xc2, t == TENC - 1);
    }

    float* ob = out + (size_t)b0 * (PLEN * OUTD);

    // ---- autoregressive decoder ----
    for (int d = 0; d < PLEN - 1; ++d) {
        read_y();
        if (tid == 0) {
            *reinterpret_cast<float2*>(ob + 0 * (PLEN * OUTD) + d * 2) = make_float2(yv0.x, yv1.x);
            *reinterpret_cast<float2*>(ob + 1 * (PLEN * OUTD) + d * 2) = make_float2(yv0.y, yv1.y);
            *reinterpret_cast<float2*>(ob + 2 * (PLEN * OUTD) + d * 2) = make_float2(yv0.z, yv1.z);
            *reinterpret_cast<float2*>(ob + 3 * (PLEN * OUTD) + d * 2) = make_float2(yv0.w, yv1.w);
        }
        const float4 fc = *reinterpret_cast<const float4*>(fc_s + d * NB);
        lstm_step(yv0, yv1, fc, true);
    }
    read_y();
    if (tid == 0) {
        const int d = PLEN - 1;
        *reinterpret_cast<float2*>(ob + 0 * (PLEN * OUTD) + d * 2) = make_float2(yv0.x, yv1.x);
        *reinterpret_cast<float2*>(ob + 1 * (PLEN * OUTD) + d * 2) = make_float2(yv0.y, yv1.y);
        *reinterpret_cast<float2*>(ob + 2 * (PLEN * OUTD) + d * 2) = make_float2(yv0.z, yv1.z);
        *reinterpret_cast<float2*>(ob + 3 * (PLEN * OUTD) + d * 2) = make_float2(yv0.w, yv1.w);
    }
}

extern "C" void kernel_launch(void* const* d_in, const int* in_sizes, int n_in,
                              void* d_out, int out_size, void* d_ws, size_t ws_size,
                              hipStream_t stream) {
    const float* x     = (const float*)d_in[0];
    const float* force = (const float*)d_in[1];
    const float* W_ih  = (const float*)d_in[2];
    const float* W_hh  = (const float*)d_in[3];
    const float* b_ih  = (const float*)d_in[4];
    const float* b_hh  = (const float*)d_in[5];
    const float* W_out = (const float*)d_in[6];
    const float* b_out = (const float*)d_in[7];
    float* out = (float*)d_out;

    lstm_forecast_kernel<<<BATCH / NB, 256, 0, stream>>>(
        x, force, W_ih, W_hh, b_ih, b_hh, W_out, b_out, out);
}

// Round 5
// 975.254 us; speedup vs baseline: 1.2000x; 1.2000x over previous
//
#include <hip/hip_runtime.h>

#define Hh 64
#define INPUT 3
#define OUTD 2
#define BATCH 1024
#define NB 2                  // batches per block
#define TENC 512
#define PLEN 300

#define LOG2E 1.44269504088896340736f

__device__ __forceinline__ float exp2_(float x) { return __builtin_amdgcn_exp2f(x); }
__device__ __forceinline__ float rcp_(float x)  { return __builtin_amdgcn_rcpf(x); }
__device__ __forceinline__ float tanh_(float x) {
    float t = exp2_(x * (2.0f * LOG2E));
    return fmaf(-2.0f, rcp_(1.0f + t), 1.0f);
}

// quad broadcast (lanes 4k..4k+3 all get quad-lane Q)
#define QUADB(dst, src, pat)                                                   \
    dst = __int_as_float(__builtin_amdgcn_update_dpp(                          \
        0, __float_as_int(src), (pat), 0xF, 0xF, true))

// xor-4 swizzle within 32-lane groups (BitMode: and=0x1F, xor=4)
#define SWZ_XOR4(x) __int_as_float(__builtin_amdgcn_ds_swizzle(__float_as_int(x), 0x101F))

// 4 MACs of one weight float4 against h[K..K+3] (broadcast b128 read)
#define MACH(W, K)                                                             \
    {                                                                          \
        const float4 hv = *reinterpret_cast<const float4*>(hb + (K));          \
        a0 = fmaf((W).x, hv.x, a0); a1 = fmaf((W).y, hv.y, a1);                \
        a0 = fmaf((W).z, hv.z, a0); a1 = fmaf((W).w, hv.w, a1);                \
    }

__global__ __launch_bounds__(512, 4)
void lstm_forecast_kernel(const float* __restrict__ x,
                          const float* __restrict__ force,
                          const float* __restrict__ W_ih,
                          const float* __restrict__ W_hh,
                          const float* __restrict__ b_ih,
                          const float* __restrict__ b_hh,
                          const float* __restrict__ W_out,
                          const float* __restrict__ b_out,
                          float* __restrict__ out)
{
    const int tid  = threadIdx.x;
    const int lane = tid & 63;
    const int wv   = tid >> 6;            // wave 0..7
    const int g    = lane & 3;            // gate 0=i 1=f 2=g 3=o
    const int half = (lane >> 2) & 1;     // which 32-col half of the row
    const int ulo  = lane >> 3;           // unit-local 0..7
    const int u    = wv * 8 + ulo;        // hidden unit 0..63
    const int row  = (g << 6) + u;        // weight row
    const int b0   = blockIdx.x * NB;

    __shared__ __align__(16) float x_s[NB][TENC * 4];     // 16 KB (stride-4 pad)
    __shared__ __align__(16) float f_s[NB][PLEN - 1];     // ~2.4 KB
    __shared__ __align__(16) float h_s[2][NB][Hh];        // 1 KB
    __shared__ __align__(16) float y_s[2][NB][2][8];      // 512 B [ph][b][out][wv]

    // ---- stage x (coalesced read, stride-4 padded write for b128 step reads) ----
    for (int i = tid; i < TENC * INPUT * NB; i += 512) {
        const int bb  = i / (TENC * INPUT);
        const int rem = i - bb * (TENC * INPUT);
        const int t   = rem / INPUT;
        const int c_  = rem - t * INPUT;
        x_s[bb][t * 4 + c_] = x[(size_t)(b0 + bb) * (TENC * INPUT) + rem];
    }
    for (int i = tid; i < (PLEN - 1) * NB; i += 512) {
        const int bb = i / (PLEN - 1);
        const int d  = i - bb * (PLEN - 1);
        f_s[bb][d] = force[(size_t)(b0 + bb) * (PLEN - 1) + d];
    }
    if (tid < NB * Hh) h_s[0][tid >> 6][tid & 63] = 0.0f;

    // ---- per-thread weights: 8 named float4 = 32 floats (half a row) ----
    const float4* wr = reinterpret_cast<const float4*>(W_hh + (size_t)row * Hh + half * 32);
    const float4 w0 = wr[0], w1 = wr[1], w2 = wr[2], w3 = wr[3];
    const float4 w4 = wr[4], w5 = wr[5], w6 = wr[6], w7 = wr[7];

    // x-part handled by half==0 lanes only (branch-free via zero weights)
    const float hm   = (half == 0) ? 1.0f : 0.0f;
    const float wi0  = hm * W_ih[row * INPUT + 0];
    const float wi1  = hm * W_ih[row * INPUT + 1];
    const float wi2  = hm * W_ih[row * INPUT + 2];
    const float bias = hm * (b_ih[row] + b_hh[row]);

    // activation consts: a = am * rcp(1 + 2^(p*kmul)) + acK   (g==2 -> tanh)
    const float kmul = (g == 2) ? (-2.0f * LOG2E) : (-LOG2E);
    const float am   = (g == 2) ? 2.0f : 1.0f;
    const float acK  = (g == 2) ? -1.0f : 0.0f;

    const float wog = (g < 2 && half == 0) ? W_out[g * Hh + u] : 0.0f;
    const float bo0 = b_out[0], bo1 = b_out[1];

    float cA = 0.0f, cB = 0.0f;
    int   rp = 0;

    __syncthreads();

    // one LSTM cell step for batch bb
    auto cell = [&](int bb, float x0, float x1, float x2, float& c, bool do_y, int ph) {
        const float* hb = &h_s[ph][bb][half << 5];
        float a0 = fmaf(wi0, x0, bias);
        a0 = fmaf(wi1, x1, a0);
        a0 = fmaf(wi2, x2, a0);
        float a1 = 0.0f;
        MACH(w0, 0)  MACH(w1, 4)  MACH(w2, 8)  MACH(w3, 12)
        MACH(w4, 16) MACH(w5, 20) MACH(w6, 24) MACH(w7, 28)
        float p = a0 + a1;
        p += SWZ_XOR4(p);                 // combine the two row-halves

        const float e  = exp2_(p * kmul); // activation
        const float rr = rcp_(1.0f + e);
        const float a  = fmaf(am, rr, acK);

        float gi, gf, gg, go;             // gather 4 gates within the quad
        QUADB(gi, a, 0x00); QUADB(gf, a, 0x55);
        QUADB(gg, a, 0xAA); QUADB(go, a, 0xFF);

        c = fmaf(gf, c, gi * gg);
        const float h = go * tanh_(c);

        if ((lane & 7) == 0) h_s[ph ^ 1][bb][u] = h;

        if (do_y) {                       // per-wave y partials over its 8 units
            float yp = wog * h;
            yp += __shfl_xor(yp, 8, 64);
            yp += __shfl_xor(yp, 16, 64);
            yp += __shfl_xor(yp, 32, 64);
            if (g < 2 && half == 0 && ulo == 0) y_s[ph ^ 1][bb][g][wv] = yp;
        }
    };

    auto assemble = [&](int bb, int ph) -> float2 {
        const float4 q0 = *reinterpret_cast<const float4*>(&y_s[ph][bb][0][0]);
        const float4 q1 = *reinterpret_cast<const float4*>(&y_s[ph][bb][0][4]);
        const float4 q2 = *reinterpret_cast<const float4*>(&y_s[ph][bb][1][0]);
        const float4 q3 = *reinterpret_cast<const float4*>(&y_s[ph][bb][1][4]);
        return make_float2(q0.x + q0.y + q0.z + q0.w + q1.x + q1.y + q1.z + q1.w + bo0,
                           q2.x + q2.y + q2.z + q2.w + q3.x + q3.y + q3.z + q3.w + bo1);
    };

    // ---- encoder ----
    for (int t = 0; t < TENC; ++t) {
        const float4 xa = *reinterpret_cast<const float4*>(&x_s[0][t * 4]);
        const float4 xb = *reinterpret_cast<const float4*>(&x_s[1][t * 4]);
        const bool dy = (t == TENC - 1);
        cell(0, xa.x, xa.y, xa.z, cA, dy, rp);
        cell(1, xb.x, xb.y, xb.z, cB, dy, rp);
        __syncthreads();
        rp ^= 1;
    }

    // ---- autoregressive decoder ----
    for (int d = 0; d < PLEN - 1; ++d) {
        const float2 yA = assemble(0, rp);
        const float2 yB = assemble(1, rp);
        if (tid < 2) {
            const float2 v = (tid == 0) ? yA : yB;
            *reinterpret_cast<float2*>(out + (size_t)(b0 + tid) * (PLEN * OUTD) + d * OUTD) = v;
        }
        const float fA = f_s[0][d];
        const float fB = f_s[1][d];
        cell(0, yA.x, yA.y, fA, cA, true, rp);
        cell(1, yB.x, yB.y, fB, cB, true, rp);
        __syncthreads();
        rp ^= 1;
    }
    {
        const float2 yA = assemble(0, rp);
        const float2 yB = assemble(1, rp);
        if (tid < 2) {
            const float2 v = (tid == 0) ? yA : yB;
            *reinterpret_cast<float2*>(out + (size_t)(b0 + tid) * (PLEN * OUTD) + (PLEN - 1) * OUTD) = v;
        }
    }
}

extern "C" void kernel_launch(void* const* d_in, const int* in_sizes, int n_in,
                              void* d_out, int out_size, void* d_ws, size_t ws_size,
                              hipStream_t stream) {
    const float* x     = (const float*)d_in[0];
    const float* force = (const float*)d_in[1];
    const float* W_ih  = (const float*)d_in[2];
    const float* W_hh  = (const float*)d_in[3];
    const float* b_ih  = (const float*)d_in[4];
    const float* b_hh  = (const float*)d_in[5];
    const float* W_out = (const float*)d_in[6];
    const float* b_out = (const float*)d_in[7];
    float* out = (float*)d_out;

    lstm_forecast_kernel<<<BATCH / NB, 512, 0, stream>>>(
        x, force, W_ih, W_hh, b_ih, b_hh, W_out, b_out, out);
}

// Round 6
// 840.868 us; speedup vs baseline: 1.3918x; 1.1598x over previous
//
#include <hip/hip_runtime.h>

#define Hh 64
#define INPUT 3
#define OUTD 2
#define BATCH 1024
#define NB 2                  // batches per block
#define TENC 512
#define PLEN 300
#define HPAD 68               // h row pad: 16B-aligned, de-conflicts writes

#define LOG2E 1.44269504088896340736f

typedef float v2f __attribute__((ext_vector_type(2)));

__device__ __forceinline__ float exp2_(float x) { return __builtin_amdgcn_exp2f(x); }
__device__ __forceinline__ float rcp_(float x)  { return __builtin_amdgcn_rcpf(x); }
__device__ __forceinline__ float tanh_(float x) {
    float t = exp2_(x * (2.0f * LOG2E));
    return fmaf(-2.0f, rcp_(1.0f + t), 1.0f);
}

// quad broadcast via DPP: all 4 lanes of a quad get quad-lane Q's value
#define QUADB(dst, src, pat)                                                   \
    dst = __int_as_float(__builtin_amdgcn_update_dpp(                          \
        0, __float_as_int(src), (pat), 0xF, 0xF, true))

#define PKFMA(acc, w, h) (acc) = __builtin_elementwise_fma((w), (h), (acc))

// force the 32 weight pairs into arch VGPRs every iteration (zero instructions)
#define PIN8(p)                                                                \
    asm volatile("" : "+v"(W[(p)]), "+v"(W[(p)+1]), "+v"(W[(p)+2]),            \
                      "+v"(W[(p)+3]), "+v"(W[(p)+4]), "+v"(W[(p)+5]),          \
                      "+v"(W[(p)+6]), "+v"(W[(p)+7]))

__global__ __launch_bounds__(256, 2)
void lstm_forecast_kernel(const float* __restrict__ x,
                          const float* __restrict__ force,
                          const float* __restrict__ W_ih,
                          const float* __restrict__ W_hh,
                          const float* __restrict__ b_ih,
                          const float* __restrict__ b_hh,
                          const float* __restrict__ W_out,
                          const float* __restrict__ b_out,
                          float* __restrict__ out)
{
    const int tid  = threadIdx.x;
    const int g    = tid & 3;            // gate 0=i 1=f 2=g 3=o (quad-local)
    const int u    = tid >> 2;           // hidden unit 0..63
    const int lane = tid & 63;
    const int wv   = tid >> 6;           // wave 0..3
    const int r    = (g << 6) + u;       // weight row
    const int b0   = blockIdx.x * NB;

    __shared__ __align__(16) float x_s[NB][TENC * 4];   // 16 KB, [b][t*4+c]
    __shared__ __align__(16) float f_s[NB][PLEN - 1];   // ~2.4 KB
    __shared__ __align__(16) float h_s[2][NB][HPAD];    // ~1.1 KB
    __shared__ __align__(16) float y_s[2][NB][4][2];    // 128 B [ph][b][wv][g]

    // ---- stage x / force (coalesced global reads, padded LDS writes) ----
    for (int i = tid; i < TENC * INPUT * NB; i += 256) {
        const int bb  = i / (TENC * INPUT);
        const int rem = i - bb * (TENC * INPUT);
        const int t   = rem / INPUT;
        const int c_  = rem - t * INPUT;
        x_s[bb][t * 4 + c_] = x[(size_t)(b0 + bb) * (TENC * INPUT) + rem];
    }
    for (int i = tid; i < (PLEN - 1) * NB; i += 256) {
        const int bb = i / (PLEN - 1);
        const int d  = i - bb * (PLEN - 1);
        f_s[bb][d] = force[(size_t)(b0 + bb) * (PLEN - 1) + d];
    }
    if (tid < NB * HPAD) (&h_s[0][0][0])[tid] = 0.0f;

    // ---- per-thread weights: full row r as 32 v2f (64 floats) ----
    v2f W[32];
    {
        const v2f* wr = reinterpret_cast<const v2f*>(W_hh + (size_t)r * Hh);
        #pragma unroll
        for (int j = 0; j < 32; ++j) W[j] = wr[j];
    }
    const float wi0  = W_ih[r * INPUT + 0];
    const float wi1  = W_ih[r * INPUT + 1];
    const float wi2  = W_ih[r * INPUT + 2];
    const float bias = b_ih[r] + b_hh[r];

    // branch-free activation constants: a = am * rcp(1 + 2^(p*kmul)) + acK
    const float kmul = (g == 2) ? (-2.0f * LOG2E) : (-LOG2E);
    const float am   = (g == 2) ? 2.0f : 1.0f;
    const float acK  = (g == 2) ? -1.0f : 0.0f;

    const float wog = (g < 2) ? W_out[g * Hh + u] : 0.0f;
    const float bo0 = b_out[0], bo1 = b_out[1];

    float cA = 0.0f, cB = 0.0f;
    int   rp = 0;

    __syncthreads();

    // one step: both batch-cells, 4 independent pk-fma chains, one barrier
    auto lstm_step = [&](float xA0, float xA1, float xA2,
                         float xB0, float xB1, float xB2, bool do_y) {
        PIN8(0); PIN8(8); PIN8(16); PIN8(24);
        const v2f* hpA = reinterpret_cast<const v2f*>(&h_s[rp][0][0]);
        const v2f* hpB = reinterpret_cast<const v2f*>(&h_s[rp][1][0]);

        float sA = fmaf(wi0, xA0, bias);
        sA = fmaf(wi1, xA1, sA); sA = fmaf(wi2, xA2, sA);
        float sB = fmaf(wi0, xB0, bias);
        sB = fmaf(wi1, xB1, sB); sB = fmaf(wi2, xB2, sB);

        v2f aA0 = {sA, 0.0f}, aA1 = {0.0f, 0.0f};
        v2f aB0 = {sB, 0.0f}, aB1 = {0.0f, 0.0f};
        #pragma unroll
        for (int j = 0; j < 32; j += 2) {
            PKFMA(aA0, W[j],     hpA[j]);
            PKFMA(aA1, W[j + 1], hpA[j + 1]);
            PKFMA(aB0, W[j],     hpB[j]);
            PKFMA(aB1, W[j + 1], hpB[j + 1]);
        }
        const v2f  vA   = aA0 + aA1;
        const v2f  vB   = aB0 + aB1;
        const float pA  = vA.x + vA.y;
        const float pB  = vB.x + vB.y;

        float hA, hB;
        #define GATEUPD(P, C, H)                                               \
        {                                                                      \
            const float e  = exp2_((P) * kmul);                                \
            const float rr = rcp_(1.0f + e);                                   \
            const float a  = fmaf(am, rr, acK);                                \
            float gi, gf, gg, go;                                              \
            QUADB(gi, a, 0x00); QUADB(gf, a, 0x55);                            \
            QUADB(gg, a, 0xAA); QUADB(go, a, 0xFF);                            \
            C = fmaf(gf, C, gi * gg);                                          \
            H = go * tanh_(C);                                                 \
        }
        GATEUPD(pA, cA, hA)
        GATEUPD(pB, cB, hB)
        #undef GATEUPD

        // g==0 writes batch A's h, g==1 writes batch B's (banks distinct)
        if (g < 2) h_s[rp ^ 1][g][u] = (g == 0) ? hA : hB;

        if (do_y) {
            float qA = wog * hA;          // zero for g>=2
            float qB = wog * hB;
            #pragma unroll
            for (int m = 4; m <= 32; m <<= 1) {
                qA += __shfl_xor(qA, m, 64);
                qB += __shfl_xor(qB, m, 64);
            }
            if (lane < 2) {               // lane==g here: carries out-dim g
                y_s[rp ^ 1][0][wv][lane] = qA;
                y_s[rp ^ 1][1][wv][lane] = qB;
            }
        }
        rp ^= 1;
        __syncthreads();
    };

    auto read_y = [&](int bb) -> float2 {
        const float4 q0 = *reinterpret_cast<const float4*>(&y_s[rp][bb][0][0]);
        const float4 q1 = *reinterpret_cast<const float4*>(&y_s[rp][bb][2][0]);
        return make_float2(q0.x + q0.z + q1.x + q1.z + bo0,
                           q0.y + q0.w + q1.y + q1.w + bo1);
    };

    // ---- encoder ----
    for (int t = 0; t < TENC; ++t) {
        const float4 xa = *reinterpret_cast<const float4*>(&x_s[0][t * 4]);
        const float4 xb = *reinterpret_cast<const float4*>(&x_s[1][t * 4]);
        lstm_step(xa.x, xa.y, xa.z, xb.x, xb.y, xb.z, t == TENC - 1);
    }

    // ---- autoregressive decoder ----
    for (int d = 0; d < PLEN - 1; ++d) {
        const float2 yA = read_y(0);
        const float2 yB = read_y(1);
        if (tid < NB) {
            const float2 v = (tid == 0) ? yA : yB;
            *reinterpret_cast<float2*>(out + (size_t)(b0 + tid) * (PLEN * OUTD) + d * OUTD) = v;
        }
        const float fA = f_s[0][d];
        const float fB = f_s[1][d];
        lstm_step(yA.x, yA.y, fA, yB.x, yB.y, fB, true);
    }
    {
        const float2 yA = read_y(0);
        const float2 yB = read_y(1);
        if (tid < NB) {
            const float2 v = (tid == 0) ? yA : yB;
            *reinterpret_cast<float2*>(out + (size_t)(b0 + tid) * (PLEN * OUTD) + (PLEN - 1) * OUTD) = v;
        }
    }
}

extern "C" void kernel_launch(void* const* d_in, const int* in_sizes, int n_in,
                              void* d_out, int out_size, void* d_ws, size_t ws_size,
                              hipStream_t stream) {
    const float* x     = (const float*)d_in[0];
    const float* force = (const float*)d_in[1];
    const float* W_ih  = (const float*)d_in[2];
    const float* W_hh  = (const float*)d_in[3];
    const float* b_ih  = (const float*)d_in[4];
    const float* b_hh  = (const float*)d_in[5];
    const float* W_out = (const float*)d_in[6];
    const float* b_out = (const float*)d_in[7];
    float* out = (float*)d_out;

    lstm_forecast_kernel<<<BATCH / NB, 256, 0, stream>>>(
        x, force, W_ih, W_hh, b_ih, b_hh, W_out, b_out, out);
}